// Round 2
// baseline (730.994 us; speedup 1.0000x reference)
//
#include <hip/hip_runtime.h>
#include <hip/hip_bf16.h>
#include <math.h>

#define N_NODES 50000
#define N_EDGES 800000
#define M_EDGES (N_EDGES + N_NODES)
#define NGRAPH 512

__device__ __forceinline__ float wave_max(float v){
  #pragma unroll
  for (int o = 32; o; o >>= 1) v = fmaxf(v, __shfl_xor(v, o));
  return v;
}
__device__ __forceinline__ float wave_sum(float v){
  #pragma unroll
  for (int o = 32; o; o >>= 1) v += __shfl_xor(v, o);
  return v;
}

// ---------------- CSR build (dst-major, includes self loops) ----------------
__global__ void k_count(const int* __restrict__ ei, int* __restrict__ deg){
  int e = blockIdx.x * blockDim.x + threadIdx.x;
  if (e >= M_EDGES) return;
  int dst = (e < N_EDGES) ? ei[N_EDGES + e] : (e - N_EDGES);
  atomicAdd(&deg[dst], 1);
}

__global__ void k_alloc(const int* __restrict__ deg, int* __restrict__ row_start,
                        int* __restrict__ cursor){
  int n = blockIdx.x * blockDim.x + threadIdx.x;
  if (n >= N_NODES) return;
  row_start[n] = atomicAdd(cursor, deg[n]);
}

__global__ void k_fill(const int* __restrict__ ei, const int* __restrict__ row_start,
                       int* __restrict__ fill, int* __restrict__ col){
  int e = blockIdx.x * blockDim.x + threadIdx.x;
  if (e >= M_EDGES) return;
  int src, dst;
  if (e < N_EDGES){ src = ei[e]; dst = ei[N_EDGES + e]; }
  else { src = dst = e - N_EDGES; }
  int slot = row_start[dst] + atomicAdd(&fill[dst], 1);
  col[slot] = src;
}

// ---------------- generic fp32 tiled GEMM: C[M,N] = A[M,K] @ B[K,N] ----------
// BM=BN=BK=64, 256 threads, 4x4 microtile. N,K multiples of 64; M guarded.
__global__ __launch_bounds__(256) void gemm64(const float* __restrict__ A,
                                              const float* __restrict__ B,
                                              float* __restrict__ C,
                                              int M, int N, int K){
  __shared__ float As[64][68];  // [k][m]
  __shared__ float Bs[64][68];  // [k][n]
  const int tid = threadIdx.x;
  const int tx = tid & 15, ty = tid >> 4;
  const int m0 = blockIdx.y * 64, n0 = blockIdx.x * 64;
  float acc[4][4] = {{0.f}};
  for (int kc = 0; kc < K; kc += 64){
    #pragma unroll
    for (int i = 0; i < 4; ++i){
      int f = tid + i * 256;
      int row = f >> 4, k4 = (f & 15) * 4;
      float4 v = make_float4(0.f, 0.f, 0.f, 0.f);
      if (m0 + row < M) v = *(const float4*)&A[(size_t)(m0 + row) * K + kc + k4];
      As[k4 + 0][row] = v.x; As[k4 + 1][row] = v.y;
      As[k4 + 2][row] = v.z; As[k4 + 3][row] = v.w;
    }
    #pragma unroll
    for (int i = 0; i < 4; ++i){
      int f = tid + i * 256;
      int kk = f >> 4, n4 = (f & 15) * 4;
      float4 v = *(const float4*)&B[(size_t)(kc + kk) * N + n0 + n4];
      *(float4*)&Bs[kk][n4] = v;
    }
    __syncthreads();
    #pragma unroll 8
    for (int k = 0; k < 64; ++k){
      float4 av = *(const float4*)&As[k][ty * 4];
      float4 bv = *(const float4*)&Bs[k][tx * 4];
      float a[4] = {av.x, av.y, av.z, av.w};
      float b[4] = {bv.x, bv.y, bv.z, bv.w};
      #pragma unroll
      for (int i = 0; i < 4; ++i)
        #pragma unroll
        for (int j = 0; j < 4; ++j) acc[i][j] += a[i] * b[j];
    }
    __syncthreads();
  }
  #pragma unroll
  for (int i = 0; i < 4; ++i){
    int m = m0 + ty * 4 + i;
    if (m < M){
      #pragma unroll
      for (int j = 0; j < 4; ++j) C[(size_t)m * N + n0 + tx * 4 + j] = acc[i][j];
    }
  }
}

// ---------------- conv1 attention scalars: asrc/adst [N,4] ------------------
__global__ __launch_bounds__(256) void k_att1(const float* __restrict__ h1,
                                              const float* __restrict__ a_src,
                                              const float* __restrict__ a_dst,
                                              float* __restrict__ asrc,
                                              float* __restrict__ adst){
  int n = blockIdx.x, tid = threadIdx.x;
  int h = tid >> 6, lane = tid & 63;
  float v = h1[(size_t)n * 256 + tid];
  float ps = wave_sum(v * a_src[tid]);
  float pd = wave_sum(v * a_dst[tid]);
  if (lane == 0){ asrc[n * 4 + h] = ps; adst[n * 4 + h] = pd; }
}

// ---------------- conv1 aggregate (4 heads x 64 ch), +b1, ELU ---------------
__global__ __launch_bounds__(256) void k_agg1(const float* __restrict__ h1,
                                              const int* __restrict__ col,
                                              const int* __restrict__ row_start,
                                              const int* __restrict__ degv,
                                              const float* __restrict__ asrc,
                                              const float* __restrict__ adst,
                                              const float* __restrict__ b1,
                                              float* __restrict__ out1){
  __shared__ float red[256][4];
  __shared__ float mh[4], sh[4];
  const int n = blockIdx.x, tid = threadIdx.x;
  const int base = row_start[n], dg = degv[n];
  float adv[4];
  {
    float4 a4 = *(const float4*)&adst[n * 4];
    adv[0] = a4.x; adv[1] = a4.y; adv[2] = a4.z; adv[3] = a4.w;
  }
  // phase 1: per-head max
  float lm[4] = {-3e38f, -3e38f, -3e38f, -3e38f};
  for (int j = tid; j < dg; j += 256){
    int src = col[base + j];
    float4 s4 = *(const float4*)&asrc[src * 4];
    float sv[4] = {s4.x, s4.y, s4.z, s4.w};
    #pragma unroll
    for (int h = 0; h < 4; ++h){
      float e = sv[h] + adv[h];
      e = e > 0.f ? e : 0.2f * e;
      lm[h] = fmaxf(lm[h], e);
    }
  }
  #pragma unroll
  for (int h = 0; h < 4; ++h) red[tid][h] = lm[h];
  __syncthreads();
  for (int s = 128; s > 0; s >>= 1){
    if (tid < s){
      #pragma unroll
      for (int h = 0; h < 4; ++h) red[tid][h] = fmaxf(red[tid][h], red[tid + s][h]);
    }
    __syncthreads();
  }
  if (tid < 4) mh[tid] = red[0][tid];
  __syncthreads();
  // phase 2: per-head exp-sum
  float ls[4] = {0.f, 0.f, 0.f, 0.f};
  for (int j = tid; j < dg; j += 256){
    int src = col[base + j];
    float4 s4 = *(const float4*)&asrc[src * 4];
    float sv[4] = {s4.x, s4.y, s4.z, s4.w};
    #pragma unroll
    for (int h = 0; h < 4; ++h){
      float e = sv[h] + adv[h];
      e = e > 0.f ? e : 0.2f * e;
      ls[h] += __expf(e - mh[h]);
    }
  }
  #pragma unroll
  for (int h = 0; h < 4; ++h) red[tid][h] = ls[h];
  __syncthreads();
  for (int s = 128; s > 0; s >>= 1){
    if (tid < s){
      #pragma unroll
      for (int h = 0; h < 4; ++h) red[tid][h] += red[tid + s][h];
    }
    __syncthreads();
  }
  if (tid < 4) sh[tid] = red[0][tid];
  __syncthreads();
  // phase 3: weighted accumulate; thread (h,c) owns out1[n, h*64+c]
  const int h = tid >> 6;
  const float m = mh[h], sum = sh[h], ad = adv[h];
  float acc = 0.f;
  for (int j = 0; j < dg; ++j){
    int src = col[base + j];
    float e = asrc[src * 4 + h] + ad;
    e = e > 0.f ? e : 0.2f * e;
    acc += __expf(e - m) * h1[(size_t)src * 256 + tid];
  }
  float o = acc / (sum + 1e-16f) + b1[tid];
  out1[(size_t)n * 256 + tid] = o > 0.f ? o : __expf(o) - 1.f;
}

// ---------------- conv2 attention scalars (1 head) --------------------------
__global__ __launch_bounds__(64) void k_att2(const float* __restrict__ t2,
                                             const float* __restrict__ a_src,
                                             const float* __restrict__ a_dst,
                                             float* __restrict__ asrc,
                                             float* __restrict__ adst){
  int n = blockIdx.x, lane = threadIdx.x;
  float v = t2[(size_t)n * 64 + lane];
  float ps = wave_sum(v * a_src[lane]);
  float pd = wave_sum(v * a_dst[lane]);
  if (lane == 0){ asrc[n] = ps; adst[n] = pd; }
}

// ------------- conv2 aggregate + b2 + ELU + global-att scalar ---------------
__global__ __launch_bounds__(64) void k_agg2(const float* __restrict__ t2,
                                             const int* __restrict__ col,
                                             const int* __restrict__ row_start,
                                             const int* __restrict__ degv,
                                             const float* __restrict__ asrc,
                                             const float* __restrict__ adst,
                                             const float* __restrict__ b2,
                                             const float* __restrict__ Wg,
                                             const float* __restrict__ bg,
                                             float* __restrict__ hf,
                                             float* __restrict__ attg){
  const int n = blockIdx.x, lane = threadIdx.x;
  const int base = row_start[n], dg = degv[n];
  const float ad = adst[n];
  float lm = -3e38f;
  for (int j = lane; j < dg; j += 64){
    float e = asrc[col[base + j]] + ad;
    e = e > 0.f ? e : 0.2f * e;
    lm = fmaxf(lm, e);
  }
  lm = wave_max(lm);
  float ls = 0.f;
  for (int j = lane; j < dg; j += 64){
    float e = asrc[col[base + j]] + ad;
    e = e > 0.f ? e : 0.2f * e;
    ls += __expf(e - lm);
  }
  ls = wave_sum(ls);
  float acc = 0.f;
  for (int j = 0; j < dg; ++j){
    int src = col[base + j];
    float e = asrc[src] + ad;
    e = e > 0.f ? e : 0.2f * e;
    acc += __expf(e - lm) * t2[(size_t)src * 64 + lane];
  }
  float o = acc / (ls + 1e-16f) + b2[lane];
  o = o > 0.f ? o : __expf(o) - 1.f;
  hf[(size_t)n * 64 + lane] = o;
  float p = wave_sum(o * Wg[lane]);
  if (lane == 0) attg[n] = p + bg[0];
}

// --------- per-graph softmax pooling + 2-layer classifier -------------------
__global__ __launch_bounds__(64) void k_pool(const float* __restrict__ hf,
                                             const float* __restrict__ attg,
                                             const int* __restrict__ batch,
                                             const float* __restrict__ Wc1,
                                             const float* __restrict__ bc1,
                                             const float* __restrict__ Wc2,
                                             const float* __restrict__ bc2,
                                             float* __restrict__ out){
  __shared__ float pooled[64];
  __shared__ float hid[32];
  const int g = blockIdx.x, lane = threadIdx.x;
  int lo = 0, hi = N_NODES;
  while (lo < hi){ int mid = (lo + hi) >> 1; if (batch[mid] < g) lo = mid + 1; else hi = mid; }
  const int s0 = lo;
  hi = N_NODES;
  while (lo < hi){ int mid = (lo + hi) >> 1; if (batch[mid] < g + 1) lo = mid + 1; else hi = mid; }
  const int s1 = lo;
  float lm = -3e38f;
  for (int j = s0 + lane; j < s1; j += 64) lm = fmaxf(lm, attg[j]);
  lm = wave_max(lm);
  float ls = 0.f;
  for (int j = s0 + lane; j < s1; j += 64) ls += __expf(attg[j] - lm);
  ls = wave_sum(ls);
  const float inv = 1.f / (ls + 1e-16f);
  float acc = 0.f;
  for (int j = s0; j < s1; ++j)
    acc += __expf(attg[j] - lm) * hf[(size_t)j * 64 + lane];
  pooled[lane] = acc * inv;
  __syncthreads();
  if (lane < 32){
    float t = bc1[lane];
    #pragma unroll
    for (int c = 0; c < 64; ++c) t += pooled[c] * Wc1[c * 32 + lane];
    hid[lane] = t > 0.f ? t : 0.f;
  }
  __syncthreads();
  if (lane < 2){
    float t = bc2[lane];
    #pragma unroll
    for (int c = 0; c < 32; ++c) t += hid[c] * Wc2[c * 2 + lane];
    out[g * 2 + lane] = t;
  }
}

extern "C" void kernel_launch(void* const* d_in, const int* in_sizes, int n_in,
                              void* d_out, int out_size, void* d_ws, size_t ws_size,
                              hipStream_t stream){
  const float* x    = (const float*)d_in[0];
  const int*   ei   = (const int*)d_in[1];
  const int*   batch= (const int*)d_in[2];
  const float* W1   = (const float*)d_in[3];
  const float* as1  = (const float*)d_in[4];
  const float* ad1  = (const float*)d_in[5];
  const float* b1   = (const float*)d_in[6];
  const float* W2   = (const float*)d_in[7];
  const float* as2  = (const float*)d_in[8];
  const float* ad2  = (const float*)d_in[9];
  const float* b2   = (const float*)d_in[10];
  const float* Wg   = (const float*)d_in[11];
  const float* bg   = (const float*)d_in[12];
  const float* Wc1  = (const float*)d_in[13];
  const float* bc1  = (const float*)d_in[14];
  const float* Wc2  = (const float*)d_in[15];
  const float* bc2  = (const float*)d_in[16];

  char* ws = (char*)d_ws;
  float* h1      = (float*)(ws + 0LL);            // 50000*256*4 = 51,200,000
  float* out1    = (float*)(ws + 51200000LL);     // 51,200,000
  float* t2      = (float*)(ws + 102400000LL);    // 12,800,000
  float* hf      = (float*)(ws + 115200000LL);    // 12,800,000
  float* asrc1   = (float*)(ws + 128000000LL);    // 800,000
  float* adst1   = (float*)(ws + 128800000LL);    // 800,000
  float* asrc2   = (float*)(ws + 129600000LL);    // 200,000
  float* adst2   = (float*)(ws + 129800000LL);    // 200,000
  float* attg    = (float*)(ws + 130000000LL);    // 200,000
  int*   deg     = (int*)  (ws + 130200000LL);    // 200,000
  int*   fill    = (int*)  (ws + 130400000LL);    // 200,000
  int*   cursor  = (int*)  (ws + 130600000LL);    // 256
  int*   row_st  = (int*)  (ws + 130600256LL);    // 200,000
  int*   col     = (int*)  (ws + 130800256LL);    // 3,400,000
  float* outf    = (float*)d_out;

  // zero deg, fill, cursor (contiguous region)
  hipMemsetAsync(ws + 130200000LL, 0, 400256, stream);

  k_count<<<(M_EDGES + 255) / 256, 256, 0, stream>>>(ei, deg);
  k_alloc<<<(N_NODES + 255) / 256, 256, 0, stream>>>(deg, row_st, cursor);
  k_fill<<<(M_EDGES + 255) / 256, 256, 0, stream>>>(ei, row_st, fill, col);

  gemm64<<<dim3(4, 782), 256, 0, stream>>>(x, W1, h1, N_NODES, 256, 256);
  k_att1<<<N_NODES, 256, 0, stream>>>(h1, as1, ad1, asrc1, adst1);
  k_agg1<<<N_NODES, 256, 0, stream>>>(h1, col, row_st, deg, asrc1, adst1, b1, out1);

  gemm64<<<dim3(1, 782), 256, 0, stream>>>(out1, W2, t2, N_NODES, 64, 256);
  k_att2<<<N_NODES, 64, 0, stream>>>(t2, as2, ad2, asrc2, adst2);
  k_agg2<<<N_NODES, 64, 0, stream>>>(t2, col, row_st, deg, asrc2, adst2, b2, Wg, bg, hf, attg);

  k_pool<<<NGRAPH, 64, 0, stream>>>(hf, attg, batch, Wc1, bc1, Wc2, bc2, outf);
}

// Round 3
// 613.051 us; speedup vs baseline: 1.1924x; 1.1924x over previous
//
#include <hip/hip_runtime.h>
#include <hip/hip_bf16.h>
#include <math.h>

#define N_NODES 50000
#define N_EDGES 800000
#define M_EDGES (N_EDGES + N_NODES)
#define NGRAPH 512
#define CH1 128
#define CH2 64

__device__ __forceinline__ float wave_max(float v){
  #pragma unroll
  for (int o = 32; o; o >>= 1) v = fmaxf(v, __shfl_xor(v, o));
  return v;
}
__device__ __forceinline__ float wave_sum(float v){
  #pragma unroll
  for (int o = 32; o; o >>= 1) v += __shfl_xor(v, o);
  return v;
}

// ---------------- CSR build (dst-major, includes self loops) ----------------
__global__ void k_count(const int* __restrict__ ei, int* __restrict__ deg){
  int e = blockIdx.x * blockDim.x + threadIdx.x;
  if (e >= M_EDGES) return;
  int dst = (e < N_EDGES) ? ei[N_EDGES + e] : (e - N_EDGES);
  atomicAdd(&deg[dst], 1);
}

__global__ void k_alloc(const int* __restrict__ deg, int* __restrict__ row_start,
                        int* __restrict__ cursor){
  int n = blockIdx.x * blockDim.x + threadIdx.x;
  if (n >= N_NODES) return;
  row_start[n] = atomicAdd(cursor, deg[n]);
}

__global__ void k_fill(const int* __restrict__ ei, const int* __restrict__ row_start,
                       int* __restrict__ fill, int* __restrict__ col){
  int e = blockIdx.x * blockDim.x + threadIdx.x;
  if (e >= M_EDGES) return;
  int src, dst;
  if (e < N_EDGES){ src = ei[e]; dst = ei[N_EDGES + e]; }
  else { src = dst = e - N_EDGES; }
  int slot = row_start[dst] + atomicAdd(&fill[dst], 1);
  col[slot] = src;
}

// ------------- fp32 GEMM 128x128 tile, BK=16, 8x8 microtile -----------------
// C[M,N] = A[M,K] @ B[K,N]. Requires N % 128 == 0, K % 16 == 0; M guarded.
__global__ __launch_bounds__(256) void gemm128(const float* __restrict__ A,
                                               const float* __restrict__ B,
                                               float* __restrict__ C,
                                               int M, int N, int K){
  __shared__ float As[16][132];  // [k][m], 132*4B = 528B (16B-aligned rows)
  __shared__ float Bs[16][132];  // [k][n]
  const int tid = threadIdx.x;
  const int tx = tid & 15, ty = tid >> 4;
  const int m0 = blockIdx.y * 128, n0 = blockIdx.x * 128;
  float acc[2][2][4][4];
  #pragma unroll
  for (int a = 0; a < 2; ++a)
    #pragma unroll
    for (int b = 0; b < 2; ++b)
      #pragma unroll
      for (int r = 0; r < 4; ++r)
        #pragma unroll
        for (int c = 0; c < 4; ++c) acc[a][b][r][c] = 0.f;

  for (int kc = 0; kc < K; kc += 16){
    #pragma unroll
    for (int i = 0; i < 2; ++i){
      int f = tid + 256 * i;
      int row = f >> 2, k4 = (f & 3) * 4;
      float4 v = make_float4(0.f, 0.f, 0.f, 0.f);
      if (m0 + row < M) v = *(const float4*)&A[(size_t)(m0 + row) * K + kc + k4];
      As[k4 + 0][row] = v.x; As[k4 + 1][row] = v.y;
      As[k4 + 2][row] = v.z; As[k4 + 3][row] = v.w;
    }
    #pragma unroll
    for (int i = 0; i < 2; ++i){
      int f = tid + 256 * i;
      int kk = f >> 5, n4 = (f & 31) * 4;
      *(float4*)&Bs[kk][n4] = *(const float4*)&B[(size_t)(kc + kk) * N + n0 + n4];
    }
    __syncthreads();
    #pragma unroll
    for (int kk = 0; kk < 16; ++kk){
      float4 a0 = *(const float4*)&As[kk][ty * 4];
      float4 a1 = *(const float4*)&As[kk][ty * 4 + 64];
      float4 b0 = *(const float4*)&Bs[kk][tx * 4];
      float4 b1 = *(const float4*)&Bs[kk][tx * 4 + 64];
      float am[2][4] = {{a0.x, a0.y, a0.z, a0.w}, {a1.x, a1.y, a1.z, a1.w}};
      float bn[2][4] = {{b0.x, b0.y, b0.z, b0.w}, {b1.x, b1.y, b1.z, b1.w}};
      #pragma unroll
      for (int a = 0; a < 2; ++a)
        #pragma unroll
        for (int b = 0; b < 2; ++b)
          #pragma unroll
          for (int r = 0; r < 4; ++r)
            #pragma unroll
            for (int c = 0; c < 4; ++c)
              acc[a][b][r][c] += am[a][r] * bn[b][c];
    }
    __syncthreads();
  }
  #pragma unroll
  for (int a = 0; a < 2; ++a)
    #pragma unroll
    for (int r = 0; r < 4; ++r){
      int m = m0 + a * 64 + ty * 4 + r;
      if (m < M){
        #pragma unroll
        for (int b = 0; b < 2; ++b)
          *(float4*)&C[(size_t)m * N + n0 + b * 64 + tx * 4] =
            make_float4(acc[a][b][r][0], acc[a][b][r][1], acc[a][b][r][2], acc[a][b][r][3]);
      }
    }
}

// ---------------- fp32 GEMM 64x64 tile (for N=64 GEMM2) ---------------------
__global__ __launch_bounds__(256) void gemm64(const float* __restrict__ A,
                                              const float* __restrict__ B,
                                              float* __restrict__ C,
                                              int M, int N, int K){
  __shared__ float As[64][68];
  __shared__ float Bs[64][68];
  const int tid = threadIdx.x;
  const int tx = tid & 15, ty = tid >> 4;
  const int m0 = blockIdx.y * 64, n0 = blockIdx.x * 64;
  float acc[4][4] = {{0.f}};
  for (int kc = 0; kc < K; kc += 64){
    #pragma unroll
    for (int i = 0; i < 4; ++i){
      int f = tid + i * 256;
      int row = f >> 4, k4 = (f & 15) * 4;
      float4 v = make_float4(0.f, 0.f, 0.f, 0.f);
      if (m0 + row < M) v = *(const float4*)&A[(size_t)(m0 + row) * K + kc + k4];
      As[k4 + 0][row] = v.x; As[k4 + 1][row] = v.y;
      As[k4 + 2][row] = v.z; As[k4 + 3][row] = v.w;
    }
    #pragma unroll
    for (int i = 0; i < 4; ++i){
      int f = tid + i * 256;
      int kk = f >> 4, n4 = (f & 15) * 4;
      *(float4*)&Bs[kk][n4] = *(const float4*)&B[(size_t)(kc + kk) * N + n0 + n4];
    }
    __syncthreads();
    #pragma unroll 8
    for (int k = 0; k < 64; ++k){
      float4 av = *(const float4*)&As[k][ty * 4];
      float4 bv = *(const float4*)&Bs[k][tx * 4];
      float a[4] = {av.x, av.y, av.z, av.w};
      float b[4] = {bv.x, bv.y, bv.z, bv.w};
      #pragma unroll
      for (int i = 0; i < 4; ++i)
        #pragma unroll
        for (int j = 0; j < 4; ++j) acc[i][j] += a[i] * b[j];
    }
    __syncthreads();
  }
  #pragma unroll
  for (int i = 0; i < 4; ++i){
    int m = m0 + ty * 4 + i;
    if (m < M){
      #pragma unroll
      for (int j = 0; j < 4; ++j) C[(size_t)m * N + n0 + tx * 4 + j] = acc[i][j];
    }
  }
}

// ---------------- conv1 attention scalars: asrc/adst [N,4] ------------------
__global__ __launch_bounds__(256) void k_att1(const float* __restrict__ h1,
                                              const float* __restrict__ a_src,
                                              const float* __restrict__ a_dst,
                                              float* __restrict__ asrc,
                                              float* __restrict__ adst){
  int n = blockIdx.x, tid = threadIdx.x;
  int h = tid >> 6, lane = tid & 63;
  float v = h1[(size_t)n * 256 + tid];
  float ps = wave_sum(v * a_src[tid]);
  float pd = wave_sum(v * a_dst[tid]);
  if (lane == 0){ asrc[n * 4 + h] = ps; adst[n * 4 + h] = pd; }
}

// -------- conv1 aggregate: LDS edge-weights + wave-per-edge float4 gather ---
__global__ __launch_bounds__(256) void k_agg1(const float* __restrict__ h1,
                                              const int* __restrict__ col,
                                              const int* __restrict__ row_start,
                                              const int* __restrict__ degv,
                                              const float* __restrict__ asrc,
                                              const float* __restrict__ adst,
                                              const float* __restrict__ b1,
                                              float* __restrict__ out1){
  __shared__ int    src_s[CH1];
  __shared__ float4 w4_s[CH1];
  __shared__ float  redm[4][4];   // [wave][head]
  __shared__ float  reds[4][4];
  __shared__ float  mh4[4], sh4[4];
  __shared__ float4 racc[4][64];  // per-wave partial accum
  const int n = blockIdx.x, tid = threadIdx.x;
  const int wv = tid >> 6, lane = tid & 63;
  const int base = row_start[n], dg = degv[n];
  const float4 ad4 = *(const float4*)&adst[(size_t)n * 4];

  // phase 1: per-head max over edges
  float lm0 = -3e38f, lm1 = -3e38f, lm2 = -3e38f, lm3 = -3e38f;
  for (int j = tid; j < dg; j += 256){
    const float4 s4 = *(const float4*)&asrc[(size_t)col[base + j] * 4];
    float e0 = s4.x + ad4.x; e0 = e0 > 0.f ? e0 : 0.2f * e0; lm0 = fmaxf(lm0, e0);
    float e1 = s4.y + ad4.y; e1 = e1 > 0.f ? e1 : 0.2f * e1; lm1 = fmaxf(lm1, e1);
    float e2 = s4.z + ad4.z; e2 = e2 > 0.f ? e2 : 0.2f * e2; lm2 = fmaxf(lm2, e2);
    float e3 = s4.w + ad4.w; e3 = e3 > 0.f ? e3 : 0.2f * e3; lm3 = fmaxf(lm3, e3);
  }
  lm0 = wave_max(lm0); lm1 = wave_max(lm1); lm2 = wave_max(lm2); lm3 = wave_max(lm3);
  if (lane == 0){ redm[wv][0] = lm0; redm[wv][1] = lm1; redm[wv][2] = lm2; redm[wv][3] = lm3; }
  __syncthreads();
  if (tid < 4)
    mh4[tid] = fmaxf(fmaxf(redm[0][tid], redm[1][tid]), fmaxf(redm[2][tid], redm[3][tid]));
  __syncthreads();
  const float m0 = mh4[0], m1 = mh4[1], m2 = mh4[2], m3 = mh4[3];

  // fused phase 2+3: per chunk, compute weights once into LDS, gather rows
  float ls0 = 0.f, ls1 = 0.f, ls2 = 0.f, ls3 = 0.f;
  float4 acc = make_float4(0.f, 0.f, 0.f, 0.f);
  const int hsel = lane >> 4;  // head owning channels 4*lane..4*lane+3
  for (int c0 = 0; c0 < dg; c0 += CH1){
    const int cnt = min(CH1, dg - c0);
    __syncthreads();
    if (tid < cnt){
      const int src = col[base + c0 + tid];
      const float4 s4 = *(const float4*)&asrc[(size_t)src * 4];
      float e0 = s4.x + ad4.x; e0 = e0 > 0.f ? e0 : 0.2f * e0; float w0 = __expf(e0 - m0);
      float e1 = s4.y + ad4.y; e1 = e1 > 0.f ? e1 : 0.2f * e1; float w1 = __expf(e1 - m1);
      float e2 = s4.z + ad4.z; e2 = e2 > 0.f ? e2 : 0.2f * e2; float w2 = __expf(e2 - m2);
      float e3 = s4.w + ad4.w; e3 = e3 > 0.f ? e3 : 0.2f * e3; float w3 = __expf(e3 - m3);
      ls0 += w0; ls1 += w1; ls2 += w2; ls3 += w3;
      src_s[tid] = src;
      w4_s[tid] = make_float4(w0, w1, w2, w3);
    }
    __syncthreads();
    for (int j = wv; j < cnt; j += 4){
      const float wt = ((const float*)&w4_s[j])[hsel];
      const int src = src_s[j];
      const float4 hv = *(const float4*)&h1[(size_t)src * 256 + lane * 4];
      acc.x += wt * hv.x; acc.y += wt * hv.y; acc.z += wt * hv.z; acc.w += wt * hv.w;
    }
  }
  ls0 = wave_sum(ls0); ls1 = wave_sum(ls1); ls2 = wave_sum(ls2); ls3 = wave_sum(ls3);
  if (lane == 0){ reds[wv][0] = ls0; reds[wv][1] = ls1; reds[wv][2] = ls2; reds[wv][3] = ls3; }
  racc[wv][lane] = acc;
  __syncthreads();
  if (tid < 4) sh4[tid] = reds[0][tid] + reds[1][tid] + reds[2][tid] + reds[3][tid];
  __syncthreads();
  const float inv = 1.f / (sh4[tid >> 6] + 1e-16f);
  const int c4 = tid >> 2, cm = tid & 3;
  float v = ((const float*)&racc[0][c4])[cm] + ((const float*)&racc[1][c4])[cm]
          + ((const float*)&racc[2][c4])[cm] + ((const float*)&racc[3][c4])[cm];
  float o = v * inv + b1[tid];
  out1[(size_t)n * 256 + tid] = o > 0.f ? o : __expf(o) - 1.f;
}

// ---------------- conv2 attention scalars (1 head) --------------------------
__global__ __launch_bounds__(64) void k_att2(const float* __restrict__ t2,
                                             const float* __restrict__ a_src,
                                             const float* __restrict__ a_dst,
                                             float* __restrict__ asrc,
                                             float* __restrict__ adst){
  int n = blockIdx.x, lane = threadIdx.x;
  float v = t2[(size_t)n * 64 + lane];
  float ps = wave_sum(v * a_src[lane]);
  float pd = wave_sum(v * a_dst[lane]);
  if (lane == 0){ asrc[n] = ps; adst[n] = pd; }
}

// ------- conv2 aggregate (4 edge-groups x 16 lanes x float4) + b2 + ELU -----
__global__ __launch_bounds__(64) void k_agg2(const float* __restrict__ t2,
                                             const int* __restrict__ col,
                                             const int* __restrict__ row_start,
                                             const int* __restrict__ degv,
                                             const float* __restrict__ asrc,
                                             const float* __restrict__ adst,
                                             const float* __restrict__ b2,
                                             const float* __restrict__ Wg,
                                             const float* __restrict__ bg,
                                             float* __restrict__ hf,
                                             float* __restrict__ attg){
  __shared__ int   src_s[CH2];
  __shared__ float w_s[CH2];
  const int n = blockIdx.x, lane = threadIdx.x;
  const int base = row_start[n], dg = degv[n];
  const float ad = adst[n];
  float lm = -3e38f;
  for (int j = lane; j < dg; j += 64){
    float e = asrc[col[base + j]] + ad;
    e = e > 0.f ? e : 0.2f * e;
    lm = fmaxf(lm, e);
  }
  lm = wave_max(lm);
  float ls = 0.f;
  float4 acc = make_float4(0.f, 0.f, 0.f, 0.f);
  const int eg = lane >> 4, c4 = (lane & 15) * 4;
  for (int c0 = 0; c0 < dg; c0 += CH2){
    const int cnt = min(CH2, dg - c0);
    __syncthreads();
    if (lane < cnt){
      const int src = col[base + c0 + lane];
      float e = asrc[src] + ad;
      e = e > 0.f ? e : 0.2f * e;
      float w = __expf(e - lm);
      ls += w;
      src_s[lane] = src;
      w_s[lane] = w;
    }
    __syncthreads();
    for (int j = eg; j < cnt; j += 4){
      const float wt = w_s[j];
      const float4 tv = *(const float4*)&t2[(size_t)src_s[j] * 64 + c4];
      acc.x += wt * tv.x; acc.y += wt * tv.y; acc.z += wt * tv.z; acc.w += wt * tv.w;
    }
  }
  ls = wave_sum(ls);
  #pragma unroll
  for (int o = 16; o <= 32; o <<= 1){
    acc.x += __shfl_xor(acc.x, o); acc.y += __shfl_xor(acc.y, o);
    acc.z += __shfl_xor(acc.z, o); acc.w += __shfl_xor(acc.w, o);
  }
  const float inv = 1.f / (ls + 1e-16f);
  float o0 = acc.x * inv + b2[c4 + 0]; o0 = o0 > 0.f ? o0 : __expf(o0) - 1.f;
  float o1 = acc.y * inv + b2[c4 + 1]; o1 = o1 > 0.f ? o1 : __expf(o1) - 1.f;
  float o2 = acc.z * inv + b2[c4 + 2]; o2 = o2 > 0.f ? o2 : __expf(o2) - 1.f;
  float o3 = acc.w * inv + b2[c4 + 3]; o3 = o3 > 0.f ? o3 : __expf(o3) - 1.f;
  if (eg == 0) *(float4*)&hf[(size_t)n * 64 + c4] = make_float4(o0, o1, o2, o3);
  float p = (eg == 0)
          ? (o0 * Wg[c4] + o1 * Wg[c4 + 1] + o2 * Wg[c4 + 2] + o3 * Wg[c4 + 3]) : 0.f;
  p = wave_sum(p);
  if (lane == 0) attg[n] = p + bg[0];
}

// --------- per-graph softmax pooling + 2-layer classifier -------------------
__global__ __launch_bounds__(64) void k_pool(const float* __restrict__ hf,
                                             const float* __restrict__ attg,
                                             const int* __restrict__ batch,
                                             const float* __restrict__ Wc1,
                                             const float* __restrict__ bc1,
                                             const float* __restrict__ Wc2,
                                             const float* __restrict__ bc2,
                                             float* __restrict__ out){
  __shared__ float pooled[64];
  __shared__ float hid[32];
  const int g = blockIdx.x, lane = threadIdx.x;
  int lo = 0, hi = N_NODES;
  while (lo < hi){ int mid = (lo + hi) >> 1; if (batch[mid] < g) lo = mid + 1; else hi = mid; }
  const int s0 = lo;
  hi = N_NODES;
  while (lo < hi){ int mid = (lo + hi) >> 1; if (batch[mid] < g + 1) lo = mid + 1; else hi = mid; }
  const int s1 = lo;
  float lm = -3e38f;
  for (int j = s0 + lane; j < s1; j += 64) lm = fmaxf(lm, attg[j]);
  lm = wave_max(lm);
  float ls = 0.f;
  for (int j = s0 + lane; j < s1; j += 64) ls += __expf(attg[j] - lm);
  ls = wave_sum(ls);
  const float inv = 1.f / (ls + 1e-16f);
  float acc = 0.f;
  for (int j = s0; j < s1; ++j)
    acc += __expf(attg[j] - lm) * hf[(size_t)j * 64 + lane];
  pooled[lane] = acc * inv;
  __syncthreads();
  if (lane < 32){
    float t = bc1[lane];
    #pragma unroll
    for (int c = 0; c < 64; ++c) t += pooled[c] * Wc1[c * 32 + lane];
    hid[lane] = t > 0.f ? t : 0.f;
  }
  __syncthreads();
  if (lane < 2){
    float t = bc2[lane];
    #pragma unroll
    for (int c = 0; c < 32; ++c) t += hid[c] * Wc2[c * 2 + lane];
    out[g * 2 + lane] = t;
  }
}

extern "C" void kernel_launch(void* const* d_in, const int* in_sizes, int n_in,
                              void* d_out, int out_size, void* d_ws, size_t ws_size,
                              hipStream_t stream){
  const float* x    = (const float*)d_in[0];
  const int*   ei   = (const int*)d_in[1];
  const int*   batch= (const int*)d_in[2];
  const float* W1   = (const float*)d_in[3];
  const float* as1  = (const float*)d_in[4];
  const float* ad1  = (const float*)d_in[5];
  const float* b1   = (const float*)d_in[6];
  const float* W2   = (const float*)d_in[7];
  const float* as2  = (const float*)d_in[8];
  const float* ad2  = (const float*)d_in[9];
  const float* b2   = (const float*)d_in[10];
  const float* Wg   = (const float*)d_in[11];
  const float* bg   = (const float*)d_in[12];
  const float* Wc1  = (const float*)d_in[13];
  const float* bc1  = (const float*)d_in[14];
  const float* Wc2  = (const float*)d_in[15];
  const float* bc2  = (const float*)d_in[16];

  char* ws = (char*)d_ws;
  float* h1      = (float*)(ws + 0LL);            // 51,200,000 B
  float* out1    = (float*)(ws + 51200000LL);     // 51,200,000 B
  float* t2      = (float*)(ws + 102400000LL);    // 12,800,000 B
  float* hf      = (float*)(ws + 115200000LL);    // 12,800,000 B
  float* asrc1   = (float*)(ws + 128000000LL);    // 800,000 B
  float* adst1   = (float*)(ws + 128800000LL);    // 800,000 B
  float* asrc2   = (float*)(ws + 129600000LL);    // 200,000 B
  float* adst2   = (float*)(ws + 129800000LL);    // 200,000 B
  float* attg    = (float*)(ws + 130000000LL);    // 200,000 B
  int*   deg     = (int*)  (ws + 130200000LL);    // 200,000 B
  int*   fill    = (int*)  (ws + 130400000LL);    // 200,000 B
  int*   cursor  = (int*)  (ws + 130600000LL);    // 256 B
  int*   row_st  = (int*)  (ws + 130600256LL);    // 200,000 B
  int*   col     = (int*)  (ws + 130800256LL);    // 3,400,000 B
  float* outf    = (float*)d_out;

  hipMemsetAsync(ws + 130200000LL, 0, 400256, stream);

  k_count<<<(M_EDGES + 255) / 256, 256, 0, stream>>>(ei, deg);
  k_alloc<<<(N_NODES + 255) / 256, 256, 0, stream>>>(deg, row_st, cursor);
  k_fill<<<(M_EDGES + 255) / 256, 256, 0, stream>>>(ei, row_st, fill, col);

  gemm128<<<dim3(2, 391), 256, 0, stream>>>(x, W1, h1, N_NODES, 256, 256);
  k_att1<<<N_NODES, 256, 0, stream>>>(h1, as1, ad1, asrc1, adst1);
  k_agg1<<<N_NODES, 256, 0, stream>>>(h1, col, row_st, deg, asrc1, adst1, b1, out1);

  gemm64<<<dim3(1, 782), 256, 0, stream>>>(out1, W2, t2, N_NODES, 64, 256);
  k_att2<<<N_NODES, 64, 0, stream>>>(t2, as2, ad2, asrc2, adst2);
  k_agg2<<<N_NODES, 64, 0, stream>>>(t2, col, row_st, deg, asrc2, adst2, b2, Wg, bg, hf, attg);

  k_pool<<<NGRAPH, 64, 0, stream>>>(hf, attg, batch, Wc1, bc1, Wc2, bc2, outf);
}